// Round 3
// baseline (1570.916 us; speedup 1.0000x reference)
//
#include <hip/hip_runtime.h>
#include <math.h>

// Problem constants (B,C,H,W fixed by the reference)
#define BB 4
#define CC 16
#define HH 256
#define WW 256
#define NN (HH*WW)        // 65536 pixels per batch
#define MM 256            // superpixels
#define CROW 20           // padded center row: c[0..17], [18]=||c||^2, [19]=pad
#define PIX 32            // pixels per sub-tile
#define TSUB 4            // sub-tiles per block (128 px/block)
#define PIXPERBLK (PIX*TSUB)
#define CHUNKS (NN/PIXPERBLK)   // 512 chunks per batch
#define NSLICE 8          // gacc contention-splitting slices

// ---------------------------------------------------------------------------
// Initial centers: 16x16 block means of features + analytic xy means + ||c||^2
// ---------------------------------------------------------------------------
__global__ void init_centers(const float* __restrict__ feat, float* __restrict__ cbuf)
{
    const int b    = blockIdx.x >> 8;
    const int m    = blockIdx.x & 255;
    const int lane = threadIdx.x;          // 0..63
    const int sy = m >> 4, sx = m & 15;

    float cvals[16];
#pragma unroll
    for (int d = 0; d < 16; ++d) {
        float v = 0.f;
#pragma unroll
        for (int k = 0; k < 4; ++k) {
            int q  = lane + (k << 6);            // 0..255 within 16x16 block
            int py = q >> 4, px = q & 15;
            int n  = (sy*16 + py)*WW + sx*16 + px;
            v += feat[((b*CC + d) << 16) + n];
        }
#pragma unroll
        for (int off = 32; off; off >>= 1) v += __shfl_down(v, off);
        cvals[d] = v * (1.f/256.f);
    }
    if (lane == 0) {
        float* row = cbuf + (b*MM + m)*CROW;
        float cn2 = 0.f;
#pragma unroll
        for (int d = 0; d < 16; ++d) { row[d] = cvals[d]; cn2 = fmaf(cvals[d], cvals[d], cn2); }
        float cx = (sx*16 + 7.5f) * (1.f/256.f);
        float cy = (sy*16 + 7.5f) * (1.f/256.f);
        row[16] = cx; row[17] = cy;
        cn2 = fmaf(cx, cx, cn2);
        cn2 = fmaf(cy, cy, cn2);
        row[18] = cn2;
        row[19] = 0.f;
    }
}

// ---------------------------------------------------------------------------
// Pre-transpose: pixel rows {p[0..17], ||p||^2, 0} into the first 20 floats of
// each 256-float Q output row (d_out doubles as scratch; final iter overwrites)
// ---------------------------------------------------------------------------
__global__ void build_pt(const float* __restrict__ feat, float* pt)
{
    const int b = blockIdx.x >> 8;
    const int n = ((blockIdx.x & 255) << 8) | threadIdx.x;
    float v[16];
#pragma unroll
    for (int d = 0; d < 16; ++d) v[d] = feat[((b*CC + d) << 16) + n];
    float x = (float)(n & 255) * (1.f/256.f);
    float y = (float)(n >> 8) * (1.f/256.f);
    float pn2 = 0.f;
#pragma unroll
    for (int d = 0; d < 16; ++d) pn2 = fmaf(v[d], v[d], pn2);
    pn2 = fmaf(x, x, pn2);
    pn2 = fmaf(y, y, pn2);
    float4* row = reinterpret_cast<float4*>(pt + ((size_t)(b*NN + n) << 8));
    row[0] = make_float4(v[0],  v[1],  v[2],  v[3]);
    row[1] = make_float4(v[4],  v[5],  v[6],  v[7]);
    row[2] = make_float4(v[8],  v[9],  v[10], v[11]);
    row[3] = make_float4(v[12], v[13], v[14], v[15]);
    row[4] = make_float4(x, y, pn2, 0.f);
}

// ---------------------------------------------------------------------------
// Fused iteration kernel. thread = m; centers + e in registers; p rows read as
// wave-uniform loads from pt; softmax sums via register reduce-scatter.
// ---------------------------------------------------------------------------
template<bool FINAL>
__global__ __launch_bounds__(256, 4)
void ssn_iter(const float* pt, const float* __restrict__ cbuf,
              float* __restrict__ gacc, float* qout)
{
    __shared__ float ssum_s[4][PIX];
    __shared__ float w_s[PIX];

    const int tid   = threadIdx.x;        // = m
    const int b     = blockIdx.x >> 9;
    const int chunk = blockIdx.x & (CHUNKS-1);
    const int n_base = chunk * PIXPERBLK;
    const int lane  = tid & 63;
    const int wv    = tid >> 6;

    // center registers
    float c[18], cn2;
    {
        const float4* cv = reinterpret_cast<const float4*>(cbuf + (b*MM + tid)*CROW);
        float4 a0 = cv[0], a1 = cv[1], a2 = cv[2], a3 = cv[3], a4 = cv[4];
        c[0]=a0.x;  c[1]=a0.y;  c[2]=a0.z;  c[3]=a0.w;
        c[4]=a1.x;  c[5]=a1.y;  c[6]=a1.z;  c[7]=a1.w;
        c[8]=a2.x;  c[9]=a2.y;  c[10]=a2.z; c[11]=a2.w;
        c[12]=a3.x; c[13]=a3.y; c[14]=a3.z; c[15]=a3.w;
        c[16]=a4.x; c[17]=a4.y; cn2=a4.z;
    }

    float acc[19];
    if (!FINAL) {
#pragma unroll
        for (int d = 0; d < 19; ++d) acc[d] = 0.f;
    }

    const int l5  = lane & 31;
    const int pxo = ((l5&1)<<4) | ((l5&2)<<2) | (l5&4) | ((l5&8)>>2) | ((l5&16)>>4);

    for (int t = 0; t < TSUB; ++t) {
        const float* prow = pt + ((size_t)(b*NN + n_base + t*PIX) << 8);

        // ---- phase 1: e[px] = exp(-dist(px, m)) into registers ----
        float e[PIX];
#pragma unroll
        for (int px = 0; px < PIX; ++px) {
            const float4* pv = reinterpret_cast<const float4*>(prow + ((size_t)px << 8));
            float4 q0 = pv[0], q1 = pv[1], q2 = pv[2], q3 = pv[3], q4 = pv[4];
            float dA, dB;
            dA = q0.x*c[0];             dB = q0.y*c[1];
            dA = fmaf(q0.z, c[2],  dA); dB = fmaf(q0.w, c[3],  dB);
            dA = fmaf(q1.x, c[4],  dA); dB = fmaf(q1.y, c[5],  dB);
            dA = fmaf(q1.z, c[6],  dA); dB = fmaf(q1.w, c[7],  dB);
            dA = fmaf(q2.x, c[8],  dA); dB = fmaf(q2.y, c[9],  dB);
            dA = fmaf(q2.z, c[10], dA); dB = fmaf(q2.w, c[11], dB);
            dA = fmaf(q3.x, c[12], dA); dB = fmaf(q3.y, c[13], dB);
            dA = fmaf(q3.z, c[14], dA); dB = fmaf(q3.w, c[15], dB);
            dA = fmaf(q4.x, c[16], dA); dB = fmaf(q4.y, c[17], dB);
            float d2   = fmaf(-2.f, dA + dB, q4.z + cn2);   // q4.z = ||p||^2
            float dist = __builtin_amdgcn_sqrtf(fmaxf(d2, 1e-12f));
            e[px] = __expf(-dist);
        }

        // ---- cross-thread sum over m: register reduce-scatter + butterfly ----
        float s[16];
        {
            const bool hi = (lane & 1);
#pragma unroll
            for (int k = 0; k < 16; ++k) {
                float a = e[k], bq = e[k+16];
                float recv = __shfl_xor(hi ? a : bq, 1);
                s[k] = (hi ? bq : a) + recv;
            }
        }
#define RS_ROUND(MASK, H) { const bool hi = (lane & (MASK)); \
        _Pragma("unroll") \
        for (int k = 0; k < (H); ++k) { \
            float a = s[k], bq = s[k+(H)]; \
            float recv = __shfl_xor(hi ? a : bq, (MASK)); \
            s[k] = (hi ? bq : a) + recv; } }
        RS_ROUND(2, 8)
        RS_ROUND(4, 4)
        RS_ROUND(8, 2)
        RS_ROUND(16, 1)
#undef RS_ROUND
        s[0] += __shfl_xor(s[0], 32);
        if (lane < 32) ssum_s[wv][pxo] = s[0];
        __syncthreads();
        if (tid < 32) {
            float tot = ssum_s[0][tid] + ssum_s[1][tid] + ssum_s[2][tid] + ssum_s[3][tid];
            w_s[tid] = 1.0f / tot;
        }
        __syncthreads();

        // ---- phase 2 ----
        if (FINAL) {
            float* qb = qout + ((size_t)(b*NN + n_base + t*PIX) << 8) + tid;
#pragma unroll
            for (int px = 0; px < PIX; ++px)
                qb[(size_t)px << 8] = e[px] * w_s[px];
        } else {
#pragma unroll
            for (int px = 0; px < PIX; ++px) {
                const float4* pv = reinterpret_cast<const float4*>(prow + ((size_t)px << 8));
                float4 q0 = pv[0], q1 = pv[1], q2 = pv[2], q3 = pv[3], q4 = pv[4];
                float ew = e[px] * w_s[px];
                acc[0]  = fmaf(ew, q0.x, acc[0]);   acc[1]  = fmaf(ew, q0.y, acc[1]);
                acc[2]  = fmaf(ew, q0.z, acc[2]);   acc[3]  = fmaf(ew, q0.w, acc[3]);
                acc[4]  = fmaf(ew, q1.x, acc[4]);   acc[5]  = fmaf(ew, q1.y, acc[5]);
                acc[6]  = fmaf(ew, q1.z, acc[6]);   acc[7]  = fmaf(ew, q1.w, acc[7]);
                acc[8]  = fmaf(ew, q2.x, acc[8]);   acc[9]  = fmaf(ew, q2.y, acc[9]);
                acc[10] = fmaf(ew, q2.z, acc[10]);  acc[11] = fmaf(ew, q2.w, acc[11]);
                acc[12] = fmaf(ew, q3.x, acc[12]);  acc[13] = fmaf(ew, q3.y, acc[13]);
                acc[14] = fmaf(ew, q3.z, acc[14]);  acc[15] = fmaf(ew, q3.w, acc[15]);
                acc[16] = fmaf(ew, q4.x, acc[16]);  acc[17] = fmaf(ew, q4.y, acc[17]);
                acc[18] += ew;
            }
        }
    }

    if (!FINAL) {
        float* dst = gacc + (((chunk & (NSLICE-1))*BB + b)*MM + tid)*19;
#pragma unroll
        for (int d = 0; d < 19; ++d)
            atomicAdd(&dst[d], acc[d]);
    }
}

// ---------------------------------------------------------------------------
// Sum NSLICE slices; c = num/(den+1e-6); recompute ||c||^2; optional cf out
// ---------------------------------------------------------------------------
__global__ void finalize_centers(const float* __restrict__ gacc, float* __restrict__ cbuf,
                                 float* __restrict__ cfout, int write_cf)
{
    const int b = blockIdx.x;
    const int m = threadIdx.x;
    float a[19];
#pragma unroll
    for (int d = 0; d < 19; ++d) a[d] = 0.f;
#pragma unroll
    for (int sl = 0; sl < NSLICE; ++sl) {
        const float* g = gacc + ((sl*BB + b)*MM + m)*19;
#pragma unroll
        for (int d = 0; d < 19; ++d) a[d] += g[d];
    }
    float den = a[18] + 1e-6f;
    float cvals[18];
    float cn2 = 0.f;
#pragma unroll
    for (int d = 0; d < 18; ++d) {
        float cv = a[d] / den;
        cvals[d] = cv;
        cn2 = fmaf(cv, cv, cn2);
    }
    float* row = cbuf + (b*MM + m)*CROW;
#pragma unroll
    for (int d = 0; d < 18; ++d) row[d] = cvals[d];
    row[18] = cn2;
    row[19] = 0.f;
    if (write_cf) {
#pragma unroll
        for (int d = 0; d < 16; ++d)
            cfout[((b*CC + d) << 8) + m] = cvals[d];
    }
}

// ---------------------------------------------------------------------------
extern "C" void kernel_launch(void* const* d_in, const int* in_sizes, int n_in,
                              void* d_out, int out_size, void* d_ws, size_t ws_size,
                              hipStream_t stream)
{
    const float* feat = (const float*)d_in[0];
    float* dout = (float*)d_out;

    float* cbuf = (float*)d_ws;                         // BB*MM*CROW floats
    float* gacc = cbuf + BB*MM*CROW;                    // NSLICE*BB*MM*19 floats

    float* qout  = dout;                                // [B, N, M]
    float* cfout = dout + (size_t)BB*NN*MM;             // [B, C, M]
    float* pt    = qout;                                // pixel rows live in Q rows

    build_pt<<<dim3(BB*256), dim3(256), 0, stream>>>(feat, pt);
    init_centers<<<dim3(BB*MM), dim3(64), 0, stream>>>(feat, cbuf);

    for (int it = 0; it < 2; ++it) {
        hipMemsetAsync(gacc, 0, (size_t)NSLICE*BB*MM*19*sizeof(float), stream);
        ssn_iter<false><<<dim3(BB*CHUNKS), dim3(256), 0, stream>>>(pt, cbuf, gacc, nullptr);
        finalize_centers<<<dim3(BB), dim3(256), 0, stream>>>(gacc, cbuf, cfout, it == 1);
    }
    ssn_iter<true><<<dim3(BB*CHUNKS), dim3(256), 0, stream>>>(pt, cbuf, nullptr, qout);
}

// Round 4
// 550.346 us; speedup vs baseline: 2.8544x; 2.8544x over previous
//
#include <hip/hip_runtime.h>
#include <math.h>

// Problem constants (B,C,H,W fixed by the reference)
#define BB 4
#define CC 16
#define HH 256
#define WW 256
#define NN (HH*WW)        // 65536 pixels per batch
#define MM 256            // superpixels
#define CROW 20           // padded center row: c[0..17], [18]=||c||^2, [19]=pad
#define PIX 32            // pixels per sub-tile
#define TSUB 4            // sub-tiles per block (128 px/block)
#define PIXPERBLK (PIX*TSUB)
#define CHUNKS (NN/PIXPERBLK)   // 512 chunks per batch

// ---------------------------------------------------------------------------
// Initial centers: 16x16 block means of features + analytic xy means + ||c||^2
// ---------------------------------------------------------------------------
__global__ void init_centers(const float* __restrict__ feat, float* __restrict__ cbuf)
{
    const int b    = blockIdx.x >> 8;
    const int m    = blockIdx.x & 255;
    const int lane = threadIdx.x;          // 0..63
    const int sy = m >> 4, sx = m & 15;

    float cvals[16];
#pragma unroll
    for (int d = 0; d < 16; ++d) {
        float v = 0.f;
#pragma unroll
        for (int k = 0; k < 4; ++k) {
            int q  = lane + (k << 6);            // 0..255 within 16x16 block
            int py = q >> 4, px = q & 15;
            int n  = (sy*16 + py)*WW + sx*16 + px;
            v += feat[((b*CC + d) << 16) + n];
        }
#pragma unroll
        for (int off = 32; off; off >>= 1) v += __shfl_down(v, off);
        cvals[d] = v * (1.f/256.f);
    }
    if (lane == 0) {
        float* row = cbuf + (b*MM + m)*CROW;
        float cn2 = 0.f;
#pragma unroll
        for (int d = 0; d < 16; ++d) { row[d] = cvals[d]; cn2 = fmaf(cvals[d], cvals[d], cn2); }
        float cx = (sx*16 + 7.5f) * (1.f/256.f);
        float cy = (sy*16 + 7.5f) * (1.f/256.f);
        row[16] = cx; row[17] = cy;
        cn2 = fmaf(cx, cx, cn2);
        cn2 = fmaf(cy, cy, cn2);
        row[18] = cn2;
        row[19] = 0.f;
    }
}

// ---------------------------------------------------------------------------
// Pre-transpose: pixel rows {p[0..17], ||p||^2, 0} into the first 20 floats of
// each 256-float Q output row (d_out doubles as scratch; final iter overwrites)
// ---------------------------------------------------------------------------
__global__ void build_pt(const float* __restrict__ feat, float* pt)
{
    const int b = blockIdx.x >> 8;
    const int n = ((blockIdx.x & 255) << 8) | threadIdx.x;
    float v[16];
#pragma unroll
    for (int d = 0; d < 16; ++d) v[d] = feat[((b*CC + d) << 16) + n];
    float x = (float)(n & 255) * (1.f/256.f);
    float y = (float)(n >> 8) * (1.f/256.f);
    float pn2 = 0.f;
#pragma unroll
    for (int d = 0; d < 16; ++d) pn2 = fmaf(v[d], v[d], pn2);
    pn2 = fmaf(x, x, pn2);
    pn2 = fmaf(y, y, pn2);
    float4* row = reinterpret_cast<float4*>(pt + ((size_t)(b*NN + n) << 8));
    row[0] = make_float4(v[0],  v[1],  v[2],  v[3]);
    row[1] = make_float4(v[4],  v[5],  v[6],  v[7]);
    row[2] = make_float4(v[8],  v[9],  v[10], v[11]);
    row[3] = make_float4(v[12], v[13], v[14], v[15]);
    row[4] = make_float4(x, y, pn2, 0.f);
}

// ---------------------------------------------------------------------------
// Fused iteration kernel. thread = m; centers + e in registers; p rows read as
// wave-uniform loads from pt; softmax sums via register reduce-scatter.
// Non-final: per-block partials written NON-ATOMICALLY into the spare bytes of
// the block's Q rows (floats 32..51 for chunk<256, 64..83 for chunk>=256 —
// different cache lines than the pt data at floats 0..19).
// ---------------------------------------------------------------------------
template<bool FINAL>
__global__ __launch_bounds__(256, 4)
void ssn_iter(float* pt, const float* __restrict__ cbuf, float* qout)
{
    __shared__ float ssum_s[4][PIX];
    __shared__ float w_s[PIX];

    const int tid   = threadIdx.x;        // = m
    const int b     = blockIdx.x >> 9;
    const int chunk = blockIdx.x & (CHUNKS-1);
    const int n_base = chunk * PIXPERBLK;
    const int lane  = tid & 63;
    const int wv    = tid >> 6;

    // center registers
    float c[18], cn2;
    {
        const float4* cv = reinterpret_cast<const float4*>(cbuf + (b*MM + tid)*CROW);
        float4 a0 = cv[0], a1 = cv[1], a2 = cv[2], a3 = cv[3], a4 = cv[4];
        c[0]=a0.x;  c[1]=a0.y;  c[2]=a0.z;  c[3]=a0.w;
        c[4]=a1.x;  c[5]=a1.y;  c[6]=a1.z;  c[7]=a1.w;
        c[8]=a2.x;  c[9]=a2.y;  c[10]=a2.z; c[11]=a2.w;
        c[12]=a3.x; c[13]=a3.y; c[14]=a3.z; c[15]=a3.w;
        c[16]=a4.x; c[17]=a4.y; cn2=a4.z;
    }

    float acc[19];
    if (!FINAL) {
#pragma unroll
        for (int d = 0; d < 19; ++d) acc[d] = 0.f;
    }

    const int l5  = lane & 31;
    const int pxo = ((l5&1)<<4) | ((l5&2)<<2) | (l5&4) | ((l5&8)>>2) | ((l5&16)>>4);

    for (int t = 0; t < TSUB; ++t) {
        const float* prow = pt + ((size_t)(b*NN + n_base + t*PIX) << 8);

        // ---- phase 1: e[px] = exp(-dist(px, m)) into registers ----
        float e[PIX];
#pragma unroll
        for (int px = 0; px < PIX; ++px) {
            const float4* pv = reinterpret_cast<const float4*>(prow + ((size_t)px << 8));
            float4 q0 = pv[0], q1 = pv[1], q2 = pv[2], q3 = pv[3], q4 = pv[4];
            float dA, dB;
            dA = q0.x*c[0];             dB = q0.y*c[1];
            dA = fmaf(q0.z, c[2],  dA); dB = fmaf(q0.w, c[3],  dB);
            dA = fmaf(q1.x, c[4],  dA); dB = fmaf(q1.y, c[5],  dB);
            dA = fmaf(q1.z, c[6],  dA); dB = fmaf(q1.w, c[7],  dB);
            dA = fmaf(q2.x, c[8],  dA); dB = fmaf(q2.y, c[9],  dB);
            dA = fmaf(q2.z, c[10], dA); dB = fmaf(q2.w, c[11], dB);
            dA = fmaf(q3.x, c[12], dA); dB = fmaf(q3.y, c[13], dB);
            dA = fmaf(q3.z, c[14], dA); dB = fmaf(q3.w, c[15], dB);
            dA = fmaf(q4.x, c[16], dA); dB = fmaf(q4.y, c[17], dB);
            float d2   = fmaf(-2.f, dA + dB, q4.z + cn2);   // q4.z = ||p||^2
            float dist = __builtin_amdgcn_sqrtf(fmaxf(d2, 1e-12f));
            e[px] = __expf(-dist);
        }

        // ---- cross-thread sum over m: register reduce-scatter + butterfly ----
        float s[16];
        {
            const bool hi = (lane & 1);
#pragma unroll
            for (int k = 0; k < 16; ++k) {
                float a = e[k], bq = e[k+16];
                float recv = __shfl_xor(hi ? a : bq, 1);
                s[k] = (hi ? bq : a) + recv;
            }
        }
#define RS_ROUND(MASK, H) { const bool hi = (lane & (MASK)); \
        _Pragma("unroll") \
        for (int k = 0; k < (H); ++k) { \
            float a = s[k], bq = s[k+(H)]; \
            float recv = __shfl_xor(hi ? a : bq, (MASK)); \
            s[k] = (hi ? bq : a) + recv; } }
        RS_ROUND(2, 8)
        RS_ROUND(4, 4)
        RS_ROUND(8, 2)
        RS_ROUND(16, 1)
#undef RS_ROUND
        s[0] += __shfl_xor(s[0], 32);
        if (lane < 32) ssum_s[wv][pxo] = s[0];
        __syncthreads();
        if (tid < 32) {
            float tot = ssum_s[0][tid] + ssum_s[1][tid] + ssum_s[2][tid] + ssum_s[3][tid];
            w_s[tid] = 1.0f / tot;
        }
        __syncthreads();

        // ---- phase 2 ----
        if (FINAL) {
            float* qb = qout + ((size_t)(b*NN + n_base + t*PIX) << 8) + tid;
#pragma unroll
            for (int px = 0; px < PIX; ++px)
                qb[(size_t)px << 8] = e[px] * w_s[px];
        } else {
#pragma unroll
            for (int px = 0; px < PIX; ++px) {
                const float4* pv = reinterpret_cast<const float4*>(prow + ((size_t)px << 8));
                float4 q0 = pv[0], q1 = pv[1], q2 = pv[2], q3 = pv[3], q4 = pv[4];
                float ew = e[px] * w_s[px];
                acc[0]  = fmaf(ew, q0.x, acc[0]);   acc[1]  = fmaf(ew, q0.y, acc[1]);
                acc[2]  = fmaf(ew, q0.z, acc[2]);   acc[3]  = fmaf(ew, q0.w, acc[3]);
                acc[4]  = fmaf(ew, q1.x, acc[4]);   acc[5]  = fmaf(ew, q1.y, acc[5]);
                acc[6]  = fmaf(ew, q1.z, acc[6]);   acc[7]  = fmaf(ew, q1.w, acc[7]);
                acc[8]  = fmaf(ew, q2.x, acc[8]);   acc[9]  = fmaf(ew, q2.y, acc[9]);
                acc[10] = fmaf(ew, q2.z, acc[10]);  acc[11] = fmaf(ew, q2.w, acc[11]);
                acc[12] = fmaf(ew, q3.x, acc[12]);  acc[13] = fmaf(ew, q3.y, acc[13]);
                acc[14] = fmaf(ew, q3.z, acc[14]);  acc[15] = fmaf(ew, q3.w, acc[15]);
                acc[16] = fmaf(ew, q4.x, acc[16]);  acc[17] = fmaf(ew, q4.y, acc[17]);
                acc[18] += ew;
            }
        }
    }

    if (!FINAL) {
        // non-atomic partial flush into spare bytes of this batch's Q rows:
        // row = (b*256 + chunk%256)*256 + m, float offset 32 or 64
        float* dst = pt + (((size_t)((b*256 + (chunk & 255))*256 + tid)) << 8)
                        + 32 + ((chunk >> 8) << 5);
        float4* dv = reinterpret_cast<float4*>(dst);
        dv[0] = make_float4(acc[0],  acc[1],  acc[2],  acc[3]);
        dv[1] = make_float4(acc[4],  acc[5],  acc[6],  acc[7]);
        dv[2] = make_float4(acc[8],  acc[9],  acc[10], acc[11]);
        dv[3] = make_float4(acc[12], acc[13], acc[14], acc[15]);
        dv[4] = make_float4(acc[16], acc[17], acc[18], 0.f);
    }
}

// ---------------------------------------------------------------------------
// Sum the 512 per-chunk partials for each (b,m); produce new centers row
// (c, ||c||^2) and optionally centers_feat. block=(b,m), thread=chunk%256.
// ---------------------------------------------------------------------------
__global__ __launch_bounds__(256)
void reduce_finalize(const float* pt, float* __restrict__ cbuf,
                     float* __restrict__ cfout, int write_cf)
{
    const int b   = blockIdx.x >> 8;
    const int m   = blockIdx.x & 255;
    const int tid = threadIdx.x;          // chunk低 8 bits
    const int lane = tid & 63, wv = tid >> 6;

    const float* base = pt + (((size_t)((b*256 + tid)*256 + m)) << 8);
    const float4* r0 = reinterpret_cast<const float4*>(base + 32);  // chunk = tid
    const float4* r1 = reinterpret_cast<const float4*>(base + 64);  // chunk = tid+256
    float a[19];
    {
        float4 u0=r0[0], u1=r0[1], u2=r0[2], u3=r0[3], u4=r0[4];
        float4 w0=r1[0], w1=r1[1], w2=r1[2], w3=r1[3], w4=r1[4];
        a[0]=u0.x+w0.x;  a[1]=u0.y+w0.y;  a[2]=u0.z+w0.z;  a[3]=u0.w+w0.w;
        a[4]=u1.x+w1.x;  a[5]=u1.y+w1.y;  a[6]=u1.z+w1.z;  a[7]=u1.w+w1.w;
        a[8]=u2.x+w2.x;  a[9]=u2.y+w2.y;  a[10]=u2.z+w2.z; a[11]=u2.w+w2.w;
        a[12]=u3.x+w3.x; a[13]=u3.y+w3.y; a[14]=u3.z+w3.z; a[15]=u3.w+w3.w;
        a[16]=u4.x+w4.x; a[17]=u4.y+w4.y; a[18]=u4.z+w4.z;
    }
#pragma unroll
    for (int off = 32; off; off >>= 1) {
#pragma unroll
        for (int d = 0; d < 19; ++d) a[d] += __shfl_down(a[d], off);
    }

    __shared__ float red[4][20];
    if (lane == 0) {
#pragma unroll
        for (int d = 0; d < 19; ++d) red[wv][d] = a[d];
    }
    __syncthreads();
    if (tid == 0) {
        float s[19];
#pragma unroll
        for (int d = 0; d < 19; ++d)
            s[d] = red[0][d] + red[1][d] + red[2][d] + red[3][d];
        float den = s[18] + 1e-6f;
        float* row = cbuf + (b*MM + m)*CROW;
        float cn2 = 0.f;
#pragma unroll
        for (int d = 0; d < 18; ++d) {
            float cv = s[d] / den;
            row[d] = cv;
            cn2 = fmaf(cv, cv, cn2);
            if (write_cf && d < 16) cfout[((b*CC + d) << 8) + m] = cv;
        }
        row[18] = cn2;
        row[19] = 0.f;
    }
}

// ---------------------------------------------------------------------------
extern "C" void kernel_launch(void* const* d_in, const int* in_sizes, int n_in,
                              void* d_out, int out_size, void* d_ws, size_t ws_size,
                              hipStream_t stream)
{
    const float* feat = (const float*)d_in[0];
    float* dout = (float*)d_out;

    float* cbuf = (float*)d_ws;                         // BB*MM*CROW floats

    float* qout  = dout;                                // [B, N, M]
    float* cfout = dout + (size_t)BB*NN*MM;             // [B, C, M]
    float* pt    = qout;                                // pixel rows live in Q rows

    build_pt<<<dim3(BB*256), dim3(256), 0, stream>>>(feat, pt);
    init_centers<<<dim3(BB*MM), dim3(64), 0, stream>>>(feat, cbuf);

    for (int it = 0; it < 2; ++it) {
        ssn_iter<false><<<dim3(BB*CHUNKS), dim3(256), 0, stream>>>(pt, cbuf, nullptr);
        reduce_finalize<<<dim3(BB*MM), dim3(256), 0, stream>>>(pt, cbuf, cfout, it == 1);
    }
    ssn_iter<true><<<dim3(BB*CHUNKS), dim3(256), 0, stream>>>(pt, cbuf, qout);
}

// Round 6
// 344.193 us; speedup vs baseline: 4.5641x; 1.5989x over previous
//
#include <hip/hip_runtime.h>
#include <math.h>

// Problem constants (B,C,H,W fixed by the reference)
#define BB 4
#define CC 16
#define HH 256
#define WW 256
#define NN (HH*WW)        // 65536 pixels per batch
#define MM 256            // superpixels
#define CROW 20           // padded center row: c[0..17], [18]=||c||^2, [19]=pad
#define PIX 32            // pixels per sub-tile
#define TSUB 4            // sub-tiles per block (128 px/block)
#define PIXPERBLK (PIX*TSUB)
#define CHUNKS (NN/PIXPERBLK)   // 512 chunks per batch

// ---------------------------------------------------------------------------
// Initial centers: 16x16 block means of features + analytic xy means + ||c||^2
// ---------------------------------------------------------------------------
__global__ void init_centers(const float* __restrict__ feat, float* __restrict__ cbuf)
{
    const int b    = blockIdx.x >> 8;
    const int m    = blockIdx.x & 255;
    const int lane = threadIdx.x;          // 0..63
    const int sy = m >> 4, sx = m & 15;

    float cvals[16];
#pragma unroll
    for (int d = 0; d < 16; ++d) {
        float v = 0.f;
#pragma unroll
        for (int k = 0; k < 4; ++k) {
            int q  = lane + (k << 6);            // 0..255 within 16x16 block
            int py = q >> 4, px = q & 15;
            int n  = (sy*16 + py)*WW + sx*16 + px;
            v += feat[((b*CC + d) << 16) + n];
        }
#pragma unroll
        for (int off = 32; off; off >>= 1) v += __shfl_down(v, off);
        cvals[d] = v * (1.f/256.f);
    }
    if (lane == 0) {
        float* row = cbuf + (b*MM + m)*CROW;
        float cn2 = 0.f;
#pragma unroll
        for (int d = 0; d < 16; ++d) { row[d] = cvals[d]; cn2 = fmaf(cvals[d], cvals[d], cn2); }
        float cx = (sx*16 + 7.5f) * (1.f/256.f);
        float cy = (sy*16 + 7.5f) * (1.f/256.f);
        row[16] = cx; row[17] = cy;
        cn2 = fmaf(cx, cx, cn2);
        cn2 = fmaf(cy, cy, cn2);
        row[18] = cn2;
        row[19] = 0.f;
    }
}

// ---------------------------------------------------------------------------
// Pre-transpose: pixel rows {p[0..17], ||p||^2, 0} into the first 20 floats of
// each 256-float Q output row (d_out doubles as scratch; final iter overwrites)
// ---------------------------------------------------------------------------
__global__ void build_pt(const float* __restrict__ feat, float* pt)
{
    const int b = blockIdx.x >> 8;
    const int n = ((blockIdx.x & 255) << 8) | threadIdx.x;
    float v[16];
#pragma unroll
    for (int d = 0; d < 16; ++d) v[d] = feat[((b*CC + d) << 16) + n];
    float x = (float)(n & 255) * (1.f/256.f);
    float y = (float)(n >> 8) * (1.f/256.f);
    float pn2 = 0.f;
#pragma unroll
    for (int d = 0; d < 16; ++d) pn2 = fmaf(v[d], v[d], pn2);
    pn2 = fmaf(x, x, pn2);
    pn2 = fmaf(y, y, pn2);
    float4* row = reinterpret_cast<float4*>(pt + ((size_t)(b*NN + n) << 8));
    row[0] = make_float4(v[0],  v[1],  v[2],  v[3]);
    row[1] = make_float4(v[4],  v[5],  v[6],  v[7]);
    row[2] = make_float4(v[8],  v[9],  v[10], v[11]);
    row[3] = make_float4(v[12], v[13], v[14], v[15]);
    row[4] = make_float4(x, y, pn2, 0.f);
}

// ---------------------------------------------------------------------------
// Fused iteration kernel. thread = m; centers + e in registers.
// All 128 p-rows staged into LDS once per block (coalesced float4), then read
// as same-address ds_read_b128 broadcasts (conflict-free, compiler-managed
// lgkmcnt — no inline-asm loads). Softmax sums via register reduce-scatter.
// Non-final: per-block partials written non-atomically into spare bytes
// (floats 32..83) of the block's Q rows.
// ---------------------------------------------------------------------------
template<bool FINAL>
__global__ __launch_bounds__(256, 4)
void ssn_iter(const float* pt_ro, const float* __restrict__ cbuf,
              float* wout)   // wout: partial-flush base (non-final) or Q (final)
{
    __shared__ __align__(16) float pls[PIXPERBLK][CROW];  // 10240 B
    __shared__ float ssum_s[TSUB][4][PIX];                //  2048 B
    __shared__ float w_s[TSUB][PIX];                      //   512 B

    const int tid   = threadIdx.x;        // = m
    const int b     = blockIdx.x >> 9;
    const int chunk = blockIdx.x & (CHUNKS-1);
    const int n_base = chunk * PIXPERBLK;
    const int lane  = tid & 63;
    const int wv    = tid >> 6;

    // ---- stage 128 pixel rows (20 floats each) into LDS, coalesced ----
#pragma unroll
    for (int k = 0; k < 4; ++k) {
        int slot = tid + (k << 8);        // 0..1023 = 128 rows x 8 slots
        int row  = slot >> 3, q = slot & 7;
        if (q < 5) {
            const float4* src = reinterpret_cast<const float4*>(
                pt_ro + ((size_t)(b*NN + n_base + row) << 8)) + q;
            *reinterpret_cast<float4*>(&pls[row][q << 2]) = *src;
        }
    }

    // center registers (per-lane vector loads, once per kernel)
    float c[18], cn2;
    {
        const float4* cv = reinterpret_cast<const float4*>(cbuf + (b*MM + tid)*CROW);
        float4 a0 = cv[0], a1 = cv[1], a2 = cv[2], a3 = cv[3], a4 = cv[4];
        c[0]=a0.x;  c[1]=a0.y;  c[2]=a0.z;  c[3]=a0.w;
        c[4]=a1.x;  c[5]=a1.y;  c[6]=a1.z;  c[7]=a1.w;
        c[8]=a2.x;  c[9]=a2.y;  c[10]=a2.z; c[11]=a2.w;
        c[12]=a3.x; c[13]=a3.y; c[14]=a3.z; c[15]=a3.w;
        c[16]=a4.x; c[17]=a4.y; cn2=a4.z;
    }

    float acc[19];
    if (!FINAL) {
#pragma unroll
        for (int d = 0; d < 19; ++d) acc[d] = 0.f;
    }

    const int l5  = lane & 31;
    const int pxo = ((l5&1)<<4) | ((l5&2)<<2) | (l5&4) | ((l5&8)>>2) | ((l5&16)>>4);

    __syncthreads();   // pls ready

    for (int t = 0; t < TSUB; ++t) {
        // ---- phase 1: e[px] = exp(-dist(px, m)), p via LDS broadcast ----
        float e[PIX];
#pragma unroll
        for (int px = 0; px < PIX; ++px) {
            const float4* pv = reinterpret_cast<const float4*>(&pls[t*PIX + px][0]);
            float4 q0 = pv[0], q1 = pv[1], q2 = pv[2], q3 = pv[3], q4 = pv[4];
            float dA, dB;
            dA = q0.x*c[0];             dB = q0.y*c[1];
            dA = fmaf(q0.z, c[2],  dA); dB = fmaf(q0.w, c[3],  dB);
            dA = fmaf(q1.x, c[4],  dA); dB = fmaf(q1.y, c[5],  dB);
            dA = fmaf(q1.z, c[6],  dA); dB = fmaf(q1.w, c[7],  dB);
            dA = fmaf(q2.x, c[8],  dA); dB = fmaf(q2.y, c[9],  dB);
            dA = fmaf(q2.z, c[10], dA); dB = fmaf(q2.w, c[11], dB);
            dA = fmaf(q3.x, c[12], dA); dB = fmaf(q3.y, c[13], dB);
            dA = fmaf(q3.z, c[14], dA); dB = fmaf(q3.w, c[15], dB);
            dA = fmaf(q4.x, c[16], dA); dB = fmaf(q4.y, c[17], dB);
            float d2   = fmaf(-2.f, dA + dB, q4.z + cn2);   // q4.z = ||p||^2
            float dist = __builtin_amdgcn_sqrtf(fmaxf(d2, 1e-12f));
            e[px] = __expf(-dist);
        }

        // ---- cross-thread sum over m: register reduce-scatter + butterfly ----
        float s[16];
        {
            const bool hi = (lane & 1);
#pragma unroll
            for (int k = 0; k < 16; ++k) {
                float a = e[k], bq = e[k+16];
                float recv = __shfl_xor(hi ? a : bq, 1);
                s[k] = (hi ? bq : a) + recv;
            }
        }
#define RS_ROUND(MASK, H) { const bool hi = (lane & (MASK)); \
        _Pragma("unroll") \
        for (int k = 0; k < (H); ++k) { \
            float a = s[k], bq = s[k+(H)]; \
            float recv = __shfl_xor(hi ? a : bq, (MASK)); \
            s[k] = (hi ? bq : a) + recv; } }
        RS_ROUND(2, 8)
        RS_ROUND(4, 4)
        RS_ROUND(8, 2)
        RS_ROUND(16, 1)
#undef RS_ROUND
        s[0] += __shfl_xor(s[0], 32);
        if (lane < 32) ssum_s[t][wv][pxo] = s[0];
        __syncthreads();
        if (tid < 32) {
            float tot = ssum_s[t][0][tid] + ssum_s[t][1][tid]
                      + ssum_s[t][2][tid] + ssum_s[t][3][tid];
            w_s[t][tid] = 1.0f / tot;
        }
        __syncthreads();

        // ---- phase 2 ----
        if (FINAL) {
            float* qb = wout + ((size_t)(b*NN + n_base + t*PIX) << 8) + tid;
#pragma unroll
            for (int px = 0; px < PIX; ++px)
                qb[(size_t)px << 8] = e[px] * w_s[t][px];
        } else {
#pragma unroll
            for (int px = 0; px < PIX; ++px) {
                const float4* pv = reinterpret_cast<const float4*>(&pls[t*PIX + px][0]);
                float4 q0 = pv[0], q1 = pv[1], q2 = pv[2], q3 = pv[3], q4 = pv[4];
                float ew = e[px] * w_s[t][px];
                acc[0]  = fmaf(ew, q0.x, acc[0]);   acc[1]  = fmaf(ew, q0.y, acc[1]);
                acc[2]  = fmaf(ew, q0.z, acc[2]);   acc[3]  = fmaf(ew, q0.w, acc[3]);
                acc[4]  = fmaf(ew, q1.x, acc[4]);   acc[5]  = fmaf(ew, q1.y, acc[5]);
                acc[6]  = fmaf(ew, q1.z, acc[6]);   acc[7]  = fmaf(ew, q1.w, acc[7]);
                acc[8]  = fmaf(ew, q2.x, acc[8]);   acc[9]  = fmaf(ew, q2.y, acc[9]);
                acc[10] = fmaf(ew, q2.z, acc[10]);  acc[11] = fmaf(ew, q2.w, acc[11]);
                acc[12] = fmaf(ew, q3.x, acc[12]);  acc[13] = fmaf(ew, q3.y, acc[13]);
                acc[14] = fmaf(ew, q3.z, acc[14]);  acc[15] = fmaf(ew, q3.w, acc[15]);
                acc[16] = fmaf(ew, q4.x, acc[16]);  acc[17] = fmaf(ew, q4.y, acc[17]);
                acc[18] += ew;
            }
        }
    }

    if (!FINAL) {
        // non-atomic partial flush into spare bytes of this batch's Q rows:
        // row = (b*256 + chunk%256)*256 + m, float offset 32 or 64
        float* dst = wout + (((size_t)((b*256 + (chunk & 255))*256 + tid)) << 8)
                         + 32 + ((chunk >> 8) << 5);
        float4* dv = reinterpret_cast<float4*>(dst);
        dv[0] = make_float4(acc[0],  acc[1],  acc[2],  acc[3]);
        dv[1] = make_float4(acc[4],  acc[5],  acc[6],  acc[7]);
        dv[2] = make_float4(acc[8],  acc[9],  acc[10], acc[11]);
        dv[3] = make_float4(acc[12], acc[13], acc[14], acc[15]);
        dv[4] = make_float4(acc[16], acc[17], acc[18], 0.f);
    }
}

// ---------------------------------------------------------------------------
// Sum the 512 per-chunk partials for each (b,m); produce new centers row
// (c, ||c||^2) and optionally centers_feat. block=(b,m), thread=chunk low 8b.
// ---------------------------------------------------------------------------
__global__ __launch_bounds__(256)
void reduce_finalize(const float* pt, float* __restrict__ cbuf,
                     float* __restrict__ cfout, int write_cf)
{
    const int b   = blockIdx.x >> 8;
    const int m   = blockIdx.x & 255;
    const int tid = threadIdx.x;
    const int lane = tid & 63, wv = tid >> 6;

    const float* base = pt + (((size_t)((b*256 + tid)*256 + m)) << 8);
    const float4* r0 = reinterpret_cast<const float4*>(base + 32);  // chunk = tid
    const float4* r1 = reinterpret_cast<const float4*>(base + 64);  // chunk = tid+256
    float a[19];
    {
        float4 u0=r0[0], u1=r0[1], u2=r0[2], u3=r0[3], u4=r0[4];
        float4 w0=r1[0], w1=r1[1], w2=r1[2], w3=r1[3], w4=r1[4];
        a[0]=u0.x+w0.x;  a[1]=u0.y+w0.y;  a[2]=u0.z+w0.z;  a[3]=u0.w+w0.w;
        a[4]=u1.x+w1.x;  a[5]=u1.y+w1.y;  a[6]=u1.z+w1.z;  a[7]=u1.w+w1.w;
        a[8]=u2.x+w2.x;  a[9]=u2.y+w2.y;  a[10]=u2.z+w2.z; a[11]=u2.w+w2.w;
        a[12]=u3.x+w3.x; a[13]=u3.y+w3.y; a[14]=u3.z+w3.z; a[15]=u3.w+w3.w;
        a[16]=u4.x+w4.x; a[17]=u4.y+w4.y; a[18]=u4.z+w4.z;
    }
#pragma unroll
    for (int off = 32; off; off >>= 1) {
#pragma unroll
        for (int d = 0; d < 19; ++d) a[d] += __shfl_down(a[d], off);
    }

    __shared__ float red[4][20];
    if (lane == 0) {
#pragma unroll
        for (int d = 0; d < 19; ++d) red[wv][d] = a[d];
    }
    __syncthreads();
    if (tid == 0) {
        float s[19];
#pragma unroll
        for (int d = 0; d < 19; ++d)
            s[d] = red[0][d] + red[1][d] + red[2][d] + red[3][d];
        float den = s[18] + 1e-6f;
        float* row = cbuf + (b*MM + m)*CROW;
        float cn2 = 0.f;
#pragma unroll
        for (int d = 0; d < 18; ++d) {
            float cv = s[d] / den;
            row[d] = cv;
            cn2 = fmaf(cv, cv, cn2);
            if (write_cf && d < 16) cfout[((b*CC + d) << 8) + m] = cv;
        }
        row[18] = cn2;
        row[19] = 0.f;
    }
}

// ---------------------------------------------------------------------------
extern "C" void kernel_launch(void* const* d_in, const int* in_sizes, int n_in,
                              void* d_out, int out_size, void* d_ws, size_t ws_size,
                              hipStream_t stream)
{
    const float* feat = (const float*)d_in[0];
    float* dout = (float*)d_out;

    float* cbuf = (float*)d_ws;                         // BB*MM*CROW floats

    float* qout  = dout;                                // [B, N, M]
    float* cfout = dout + (size_t)BB*NN*MM;             // [B, C, M]
    float* pt    = qout;                                // pixel rows live in Q rows

    build_pt<<<dim3(BB*256), dim3(256), 0, stream>>>(feat, pt);
    init_centers<<<dim3(BB*MM), dim3(64), 0, stream>>>(feat, cbuf);

    for (int it = 0; it < 2; ++it) {
        ssn_iter<false><<<dim3(BB*CHUNKS), dim3(256), 0, stream>>>(pt, cbuf, pt);
        reduce_finalize<<<dim3(BB*MM), dim3(256), 0, stream>>>(pt, cbuf, cfout, it == 1);
    }
    ssn_iter<true><<<dim3(BB*CHUNKS), dim3(256), 0, stream>>>(pt, cbuf, qout);
}